// Round 7
// baseline (152.929 us; speedup 1.0000x reference)
//
#include <hip/hip_runtime.h>
#include <math.h>

// Problem constants (from reference)
#define N_S   256
#define C_IN  3
#define H_IN  270
#define W_IN  480
#define H_OUT 144
#define W_OUT 256
#define FEAT  32
#define HW_IN  (H_IN * W_IN)
#define HW_OUT (H_OUT * W_OUT)
#define ROWS  2                      // output rows per thread (R4 optimum)
#define NBLK  (N_S * H_OUT / ROWS)   // 18432

#define GAMMA_F 1.7015043497085571f
#define FOV_RAD 0.6544984694978736f   // deg2rad(37.5)
#define SQRT_2_OVER_PI 0.7978845608028654f

#define WS_R_OFF  0        // 256 * 9 floats

__device__ __forceinline__ float gelu_gamma(float x) {
    float t = tanhf(SQRT_2_OVER_PI * (x + 0.044715f * x * x * x));
    return 0.5f * x * (1.0f + t) * GAMMA_F;
}

// ---------------- Kernel A: per-sample MLP -> rotation matrix ----------------
__global__ __launch_bounds__(64) void mlp_rot_kernel(
    const float* __restrict__ eye,
    const float* __restrict__ W0, const float* __restrict__ b0,
    const float* __restrict__ W1, const float* __restrict__ b1,
    const float* __restrict__ Wp, const float* __restrict__ bp,
    float* __restrict__ wsR)
{
    __shared__ float h_s[FEAT];
    __shared__ float ang_s[3];
    __shared__ float R_s[9];
    const int n   = blockIdx.x;
    const int tid = threadIdx.x;

    if (tid < FEAT) {
        const float e0 = eye[n * 2 + 0];
        const float e1 = eye[n * 2 + 1];
        float a = fmaf(e0, W0[tid], fmaf(e1, W0[FEAT + tid], b0[tid]));
        h_s[tid] = gelu_gamma(a);
    }
    __syncthreads();
    float h1v = 0.0f;
    if (tid < FEAT) {
        float acc = b1[tid];
        #pragma unroll
        for (int k = 0; k < FEAT; ++k) acc = fmaf(h_s[k], W1[k * FEAT + tid], acc);
        h1v = gelu_gamma(acc);
    }
    __syncthreads();
    if (tid < FEAT) h_s[tid] = h1v;
    __syncthreads();
    if (tid < 3) {
        float acc = bp[tid];
        #pragma unroll
        for (int k = 0; k < FEAT; ++k) acc = fmaf(h_s[k], Wp[k * 3 + tid], acc);
        ang_s[tid] = acc;
    }
    __syncthreads();
    if (tid == 0) {
        const float cx = cosf(ang_s[0]), sx = sinf(ang_s[0]);
        const float cy = cosf(ang_s[1]), sy = sinf(ang_s[1]);
        const float cz = cosf(ang_s[2]), sz = sinf(ang_s[2]);
        R_s[0] = cz * cy; R_s[1] = cz * sy * sx - sz * cx; R_s[2] = cz * sy * cx + sz * sx;
        R_s[3] = sz * cy; R_s[4] = sz * sy * sx + cz * cx; R_s[5] = sz * sy * cx - cz * sx;
        R_s[6] = -sy;     R_s[7] = cy * sx;                R_s[8] = cy * cx;
    }
    __syncthreads();
    if (tid < 9) wsR[n * 9 + tid] = R_s[tid];
}

// ---------------- Kernel C: hot gather kernel --------------------------------
// 8-byte tap-pair load; only 4-byte alignment is guaranteed.
struct __attribute__((packed, aligned(4))) f2a { float x, y; };

// grid: 18432 blocks = 256 samples x 72 row-pairs; thread tid = output col,
// handles ROWS=2 consecutive output rows.
__global__ __launch_bounds__(256) void retina_sample_kernel(
    const float* __restrict__ stim,
    const float* __restrict__ wsR,
    float* __restrict__ out)
{
    // XCD-aware swizzle (bijective: NBLK % 8 == 0)
    const int blk  = blockIdx.x;
    const int work = ((blk & 7) * (NBLK / 8)) + (blk >> 3);
    const int n   = work / (H_OUT / ROWS);
    const int hp  = work - n * (H_OUT / ROWS);
    const int tid = threadIdx.x;   // = output w

    // rotation matrix: n is block-uniform -> scalar loads
    float Rm[9];
    #pragma unroll
    for (int i = 0; i < 9; ++i) Rm[i] = wsR[n * 9 + i];

    const float gx  = ((tid + 0.5f) * 2.0f - (float)W_OUT) * (1.0f / 144.0f);
    const float gx2 = gx * gx;

    const float* __restrict__ sbase = stim + (size_t)n * (C_IN * HW_IN);
    float* __restrict__ obase = out + (size_t)n * (C_IN * HW_OUT) + tid;

    #pragma unroll
    for (int rr = 0; rr < ROWS; ++rr) {
        const int   h  = ROWS * hp + rr;
        const float gy = ((h + 0.5f) * 2.0f - (float)H_OUT) * (1.0f / 144.0f);
        const float u  = fmaf(gy, gy, gx2);                 // r^2
        const float x  = u * (FOV_RAD * FOV_RAD);           // (k*r)^2 <= ~1.77

        // sin(k*r)/r = k * P(x), cos(k*r) = Q(x); Taylor, trunc err < 1e-8
        const float sinp = 1.0f + x * (-1.6666667e-1f + x * (8.3333333e-3f
                         + x * (-1.9841270e-4f + x * (2.7557319e-6f
                         + x * (-2.5052108e-8f)))));
        const float cosp = 1.0f + x * (-0.5f + x * (4.1666667e-2f
                         + x * (-1.3888889e-3f + x * (2.4801587e-5f
                         + x * (-2.7557319e-7f + x * 2.0876757e-9f)))));

        const float S   = FOV_RAD * sinp;                   // sin(theta)/r
        const float dxv = S * gx;
        const float dyv = S * gy;
        const float dzv = cosp;

        const float rxv = fmaf(Rm[0], dxv, fmaf(Rm[1], dyv, Rm[2] * dzv));
        const float ryv = fmaf(Rm[3], dxv, fmaf(Rm[4], dyv, Rm[5] * dzv));
        const float rzv = fmaf(Rm[6], dxv, fmaf(Rm[7], dyv, Rm[8] * dzv));

        const float z     = fmaxf(rzv, 1e-6f);
        const float inv_z = __builtin_amdgcn_rcpf(z);
        const float px = rxv * inv_z;
        const float py = ryv * inv_z;

        float fx = fmaf(px, 135.0f, 240.5f);
        float fy = fmaf(py, 135.0f, 135.5f);
        fx = fminf(fmaxf(fx, -100.0f), 100000.0f);
        fy = fminf(fmaxf(fy, -100.0f), 100000.0f);

        const float x0f = floorf(fx), y0f = floorf(fy);
        const float wx = fx - x0f,   wy = fy - y0f;
        const int x0 = (int)x0f, y0 = (int)y0f;      // padded coords
        const int cx0 = x0 - 1;                      // unpadded tap col/row
        const int cy0 = y0 - 1;

        float c00, c01, c10, c11;
        const float* __restrict__ p0;

        // fast path: all 4 taps strictly interior (~95% of pixels; the test is
        // wave-uniform except at border-crossing waves)
        if (((unsigned)cx0 <= (unsigned)(W_IN - 2)) &
            ((unsigned)cy0 <= (unsigned)(H_IN - 2))) {
            const float wl = 1.0f - wx, wt = 1.0f - wy;
            c00 = wt * wl; c01 = wt * wx;
            c10 = wy * wl; c11 = wy * wx;
            p0 = sbase + cy0 * W_IN + cx0;
        } else {
            // validity-folded weights (identical to the zero-pad ring)
            const float wxa = ((unsigned)cx0       < (unsigned)W_IN) ? (1.0f - wx) : 0.0f;
            const float wxb = ((unsigned)(cx0 + 1) < (unsigned)W_IN) ? wx          : 0.0f;
            const float wya = ((unsigned)cy0       < (unsigned)H_IN) ? (1.0f - wy) : 0.0f;
            const float wyb = ((unsigned)(cy0 + 1) < (unsigned)H_IN) ? wy          : 0.0f;

            // remap taps onto the clamped 2-wide windows [b,b+1] x [yb,yb+1]
            const int b = min(max(cx0, 0), W_IN - 2);
            const float wl = (cx0 == b) ? wxa : ((cx0 == b - 1) ? wxb : 0.0f);
            const float wr = (cx0 == b) ? wxb : ((cx0 == b + 1) ? wxa : 0.0f);
            const int yb = min(max(cy0, 0), H_IN - 2);
            const float wt = (cy0 == yb) ? wya : ((cy0 == yb - 1) ? wyb : 0.0f);
            const float wb = (cy0 == yb) ? wyb : ((cy0 == yb + 1) ? wya : 0.0f);

            c00 = wt * wl; c01 = wt * wr;
            c10 = wb * wl; c11 = wb * wr;
            p0 = sbase + yb * W_IN + b;
        }

        const float* __restrict__ q0 = p0 + W_IN;

        const f2a a0 = *reinterpret_cast<const f2a*>(p0);
        const f2a a1 = *reinterpret_cast<const f2a*>(q0);
        const f2a b0 = *reinterpret_cast<const f2a*>(p0 + HW_IN);
        const f2a b1 = *reinterpret_cast<const f2a*>(q0 + HW_IN);
        const f2a c0 = *reinterpret_cast<const f2a*>(p0 + 2 * HW_IN);
        const f2a c1 = *reinterpret_cast<const f2a*>(q0 + 2 * HW_IN);

        const float r0 = fmaf(a0.x, c00, fmaf(a0.y, c01, fmaf(a1.x, c10, a1.y * c11)));
        const float r1 = fmaf(b0.x, c00, fmaf(b0.y, c01, fmaf(b1.x, c10, b1.y * c11)));
        const float r2 = fmaf(c0.x, c00, fmaf(c0.y, c01, fmaf(c1.x, c10, c1.y * c11)));

        float* op = obase + h * W_OUT;
        __builtin_nontemporal_store(r0, op);
        __builtin_nontemporal_store(r1, op + HW_OUT);
        __builtin_nontemporal_store(r2, op + 2 * HW_OUT);
    }
}

extern "C" void kernel_launch(void* const* d_in, const int* in_sizes, int n_in,
                              void* d_out, int out_size, void* d_ws, size_t ws_size,
                              hipStream_t stream) {
    const float* stim = (const float*)d_in[0];
    const float* eye  = (const float*)d_in[1];
    const float* W0   = (const float*)d_in[2];
    const float* b0   = (const float*)d_in[3];
    const float* W1   = (const float*)d_in[4];
    const float* b1   = (const float*)d_in[5];
    const float* Wp   = (const float*)d_in[6];
    const float* bp   = (const float*)d_in[7];
    float* out = (float*)d_out;

    float* wsR = (float*)((char*)d_ws + WS_R_OFF);

    mlp_rot_kernel<<<dim3(N_S), dim3(64), 0, stream>>>(eye, W0, b0, W1, b1, Wp, bp, wsR);
    retina_sample_kernel<<<dim3(NBLK), dim3(256), 0, stream>>>(stim, wsR, out);
}

// Round 8
// 136.058 us; speedup vs baseline: 1.1240x; 1.1240x over previous
//
#include <hip/hip_runtime.h>
#include <math.h>

// Problem constants (from reference)
#define N_S   256
#define C_IN  3
#define H_IN  270
#define W_IN  480
#define H_OUT 144
#define W_OUT 256
#define FEAT  32
#define HW_IN  (H_IN * W_IN)
#define HW_OUT (H_OUT * W_OUT)
#define NBLK  (N_S * H_OUT)          // 36864: one output row per block

#define GAMMA_F 1.7015043497085571f
#define FOV_RAD 0.6544984694978736f   // deg2rad(37.5)
#define SQRT_2_OVER_PI 0.7978845608028654f

#define WS_R_OFF  0        // 256 * 9 floats

__device__ __forceinline__ float gelu_gamma(float x) {
    float t = tanhf(SQRT_2_OVER_PI * (x + 0.044715f * x * x * x));
    return 0.5f * x * (1.0f + t) * GAMMA_F;
}

// ---------------- Kernel A: per-sample MLP -> rotation matrix ----------------
__global__ __launch_bounds__(64) void mlp_rot_kernel(
    const float* __restrict__ eye,
    const float* __restrict__ W0, const float* __restrict__ b0,
    const float* __restrict__ W1, const float* __restrict__ b1,
    const float* __restrict__ Wp, const float* __restrict__ bp,
    float* __restrict__ wsR)
{
    __shared__ float h_s[FEAT];
    __shared__ float ang_s[3];
    __shared__ float R_s[9];
    const int n   = blockIdx.x;
    const int tid = threadIdx.x;

    if (tid < FEAT) {
        const float e0 = eye[n * 2 + 0];
        const float e1 = eye[n * 2 + 1];
        float a = fmaf(e0, W0[tid], fmaf(e1, W0[FEAT + tid], b0[tid]));
        h_s[tid] = gelu_gamma(a);
    }
    __syncthreads();
    float h1v = 0.0f;
    if (tid < FEAT) {
        float acc = b1[tid];
        #pragma unroll
        for (int k = 0; k < FEAT; ++k) acc = fmaf(h_s[k], W1[k * FEAT + tid], acc);
        h1v = gelu_gamma(acc);
    }
    __syncthreads();
    if (tid < FEAT) h_s[tid] = h1v;
    __syncthreads();
    if (tid < 3) {
        float acc = bp[tid];
        #pragma unroll
        for (int k = 0; k < FEAT; ++k) acc = fmaf(h_s[k], Wp[k * 3 + tid], acc);
        ang_s[tid] = acc;
    }
    __syncthreads();
    if (tid == 0) {
        const float cx = cosf(ang_s[0]), sx = sinf(ang_s[0]);
        const float cy = cosf(ang_s[1]), sy = sinf(ang_s[1]);
        const float cz = cosf(ang_s[2]), sz = sinf(ang_s[2]);
        R_s[0] = cz * cy; R_s[1] = cz * sy * sx - sz * cx; R_s[2] = cz * sy * cx + sz * sx;
        R_s[3] = sz * cy; R_s[4] = sz * sy * sx + cz * cx; R_s[5] = sz * sy * cx - cz * sx;
        R_s[6] = -sy;     R_s[7] = cy * sx;                R_s[8] = cy * cx;
    }
    __syncthreads();
    if (tid < 9) wsR[n * 9 + tid] = R_s[tid];
}

// ---------------- Kernel C: hot gather kernel --------------------------------
// 8-byte tap-pair load; only 4-byte alignment is guaranteed.
struct __attribute__((packed, aligned(4))) f2a { float x, y; };

// grid: 36864 blocks = 256 samples x 144 rows; thread tid = output col.
// One output pixel per thread: maximum TLP, shortest per-thread chain,
// 6 independent gathers in flight per thread.
__global__ __launch_bounds__(256) void retina_sample_kernel(
    const float* __restrict__ stim,
    const float* __restrict__ wsR,
    float* __restrict__ out)
{
    // XCD-aware swizzle (bijective: NBLK % 8 == 0)
    const int blk  = blockIdx.x;
    const int work = ((blk & 7) * (NBLK / 8)) + (blk >> 3);
    const int n   = work / H_OUT;
    const int h   = work - n * H_OUT;
    const int tid = threadIdx.x;   // = output w

    // rotation matrix: n is block-uniform -> scalar loads
    float Rm[9];
    #pragma unroll
    for (int i = 0; i < 9; ++i) Rm[i] = wsR[n * 9 + i];

    const float gx  = ((tid + 0.5f) * 2.0f - (float)W_OUT) * (1.0f / 144.0f);
    const float gy  = ((h   + 0.5f) * 2.0f - (float)H_OUT) * (1.0f / 144.0f);
    const float u   = fmaf(gy, gy, gx * gx);            // r^2
    const float x   = u * (FOV_RAD * FOV_RAD);          // (k*r)^2 <= ~1.77

    // sin(k*r)/r = k * P(x), cos(k*r) = Q(x); Taylor, trunc err < 1e-8
    const float sinp = 1.0f + x * (-1.6666667e-1f + x * (8.3333333e-3f
                     + x * (-1.9841270e-4f + x * (2.7557319e-6f
                     + x * (-2.5052108e-8f)))));
    const float cosp = 1.0f + x * (-0.5f + x * (4.1666667e-2f
                     + x * (-1.3888889e-3f + x * (2.4801587e-5f
                     + x * (-2.7557319e-7f + x * 2.0876757e-9f)))));

    const float S   = FOV_RAD * sinp;                   // sin(theta)/r
    const float dxv = S * gx;
    const float dyv = S * gy;
    const float dzv = cosp;

    const float rxv = fmaf(Rm[0], dxv, fmaf(Rm[1], dyv, Rm[2] * dzv));
    const float ryv = fmaf(Rm[3], dxv, fmaf(Rm[4], dyv, Rm[5] * dzv));
    const float rzv = fmaf(Rm[6], dxv, fmaf(Rm[7], dyv, Rm[8] * dzv));

    const float z     = fmaxf(rzv, 1e-6f);
    const float inv_z = __builtin_amdgcn_rcpf(z);
    const float px = rxv * inv_z;
    const float py = ryv * inv_z;

    float fx = fmaf(px, 135.0f, 240.5f);
    float fy = fmaf(py, 135.0f, 135.5f);
    fx = fminf(fmaxf(fx, -100.0f), 100000.0f);
    fy = fminf(fmaxf(fy, -100.0f), 100000.0f);

    const float x0f = floorf(fx), y0f = floorf(fy);
    const float wx = fx - x0f,   wy = fy - y0f;
    const int x0 = (int)x0f, y0 = (int)y0f;      // padded coords
    const int cx0 = x0 - 1;                      // unpadded tap col/row
    const int cy0 = y0 - 1;

    // validity-folded weights (identical to the zero-pad ring)
    const float wxa = ((unsigned)cx0       < (unsigned)W_IN) ? (1.0f - wx) : 0.0f;
    const float wxb = ((unsigned)(cx0 + 1) < (unsigned)W_IN) ? wx          : 0.0f;
    const float wya = ((unsigned)cy0       < (unsigned)H_IN) ? (1.0f - wy) : 0.0f;
    const float wyb = ((unsigned)(cy0 + 1) < (unsigned)H_IN) ? wy          : 0.0f;

    // remap taps onto the clamped 2-wide windows [b,b+1] x [yb,yb+1]
    const int b = min(max(cx0, 0), W_IN - 2);
    const float wl = (cx0 == b) ? wxa : ((cx0 == b - 1) ? wxb : 0.0f);
    const float wr = (cx0 == b) ? wxb : ((cx0 == b + 1) ? wxa : 0.0f);
    const int yb = min(max(cy0, 0), H_IN - 2);
    const float wt = (cy0 == yb) ? wya : ((cy0 == yb - 1) ? wyb : 0.0f);
    const float wb = (cy0 == yb) ? wyb : ((cy0 == yb + 1) ? wya : 0.0f);

    const float c00 = wt * wl, c01 = wt * wr;
    const float c10 = wb * wl, c11 = wb * wr;

    const float* __restrict__ sbase = stim + (size_t)n * (C_IN * HW_IN);
    const float* __restrict__ p0 = sbase + yb * W_IN + b;
    const float* __restrict__ q0 = p0 + W_IN;

    const f2a a0 = *reinterpret_cast<const f2a*>(p0);
    const f2a a1 = *reinterpret_cast<const f2a*>(q0);
    const f2a b0 = *reinterpret_cast<const f2a*>(p0 + HW_IN);
    const f2a b1 = *reinterpret_cast<const f2a*>(q0 + HW_IN);
    const f2a c0 = *reinterpret_cast<const f2a*>(p0 + 2 * HW_IN);
    const f2a c1 = *reinterpret_cast<const f2a*>(q0 + 2 * HW_IN);

    const float r0 = fmaf(a0.x, c00, fmaf(a0.y, c01, fmaf(a1.x, c10, a1.y * c11)));
    const float r1 = fmaf(b0.x, c00, fmaf(b0.y, c01, fmaf(b1.x, c10, b1.y * c11)));
    const float r2 = fmaf(c0.x, c00, fmaf(c0.y, c01, fmaf(c1.x, c10, c1.y * c11)));

    float* op = out + (size_t)n * (C_IN * HW_OUT) + h * W_OUT + tid;
    __builtin_nontemporal_store(r0, op);
    __builtin_nontemporal_store(r1, op + HW_OUT);
    __builtin_nontemporal_store(r2, op + 2 * HW_OUT);
}

extern "C" void kernel_launch(void* const* d_in, const int* in_sizes, int n_in,
                              void* d_out, int out_size, void* d_ws, size_t ws_size,
                              hipStream_t stream) {
    const float* stim = (const float*)d_in[0];
    const float* eye  = (const float*)d_in[1];
    const float* W0   = (const float*)d_in[2];
    const float* b0   = (const float*)d_in[3];
    const float* W1   = (const float*)d_in[4];
    const float* b1   = (const float*)d_in[5];
    const float* Wp   = (const float*)d_in[6];
    const float* bp   = (const float*)d_in[7];
    float* out = (float*)d_out;

    float* wsR = (float*)((char*)d_ws + WS_R_OFF);

    mlp_rot_kernel<<<dim3(N_S), dim3(64), 0, stream>>>(eye, W0, b0, W1, b1, Wp, bp, wsR);
    retina_sample_kernel<<<dim3(NBLK), dim3(256), 0, stream>>>(stim, wsR, out);
}